// Round 14
// baseline (253.350 us; speedup 1.0000x reference)
//
#include <hip/hip_runtime.h>
#include <hip/hip_fp16.h>

// Problem constants (match reference)
constexpr int   N_NODES = 80000;
constexpr int   N_EDGE  = 2560000;
constexpr int   IN_DIM  = 128;
constexpr int   H1      = 32;
constexpr int   H2      = 64;
constexpr int   NPB     = 10000;   // nodes per batch
constexpr int   NB      = 8;       // batches
constexpr int   G2_BLOCKS = N_NODES / 4;        // 20000 (4 nodes per block)
constexpr int   BLK_PER_BATCH = G2_BLOCKS / NB; // 2500

// binned-fill parameters (static bucket capacity)
constexpr int   BKT_SHIFT = 7;                       // 128 nodes per bucket
constexpr int   BKT_N     = 1 << BKT_SHIFT;          // 128
constexpr int   NBKT      = N_NODES >> BKT_SHIFT;    // 625
constexpr int   BBSTRIDE  = 16;                      // pad bucket counters to 64 B
constexpr unsigned SBKT_CAP = 4608;                  // mean 4096 + 8 sigma
constexpr int   BF_EPB    = 4096;                    // edges per binfill block
constexpr int   BF_BLOCKS = (N_EDGE + BF_EPB - 1) / BF_EPB;  // 625
constexpr int   BF_THREADS = 512;

// ---------------- seed bucket bumps with static bases ----------------
__global__ void k_initb(unsigned* __restrict__ bbump) {
    int i = blockIdx.x * blockDim.x + threadIdx.x;
    if (i < NBKT) bbump[i * BBSTRIDE] = (unsigned)i * SBKT_CAP;
}

// ------- binned fill: stage[pos] = (src<<7)|d_local, dense per bucket ------
__global__ __launch_bounds__(BF_THREADS) void k_binfill(
        const int* __restrict__ ei, unsigned* __restrict__ bbump,
        unsigned* __restrict__ stage) {
    __shared__ unsigned hist[NBKT];
    __shared__ unsigned base[NBKT];
    int t = threadIdx.x;
    int e0 = blockIdx.x * BF_EPB;
    int e1 = min(e0 + BF_EPB, N_EDGE);
    for (int i = t; i < NBKT; i += BF_THREADS) hist[i] = 0u;
    __syncthreads();
    for (int e = e0 + t; e < e1; e += BF_THREADS) {
        int d = ei[N_EDGE + e];
        atomicAdd(&hist[d >> BKT_SHIFT], 1u);
    }
    __syncthreads();
    for (int i = t; i < NBKT; i += BF_THREADS) {
        unsigned h = hist[i];
        base[i] = h ? atomicAdd(&bbump[i * BBSTRIDE], h) : 0u;
        hist[i] = 0u;
    }
    __syncthreads();
    for (int e = e0 + t; e < e1; e += BF_THREADS) {
        int s = ei[e];
        int d = ei[N_EDGE + e];
        int bkt = d >> BKT_SHIFT;
        unsigned lp = atomicAdd(&hist[bkt], 1u);
        unsigned pos = base[bkt] + lp;
        if (pos < (unsigned)(bkt + 1) * SBKT_CAP)   // capacity guard (never hit)
            stage[pos] = ((unsigned)s << BKT_SHIFT) | (unsigned)(d & (BKT_N - 1));
    }
}

// ------- place: per-bucket degrees (LDS) -> row_ptr, rend, dinv, csr -------
__global__ __launch_bounds__(256) void k_place(
        const unsigned* __restrict__ bbump, const unsigned* __restrict__ stage,
        int* __restrict__ csr, unsigned* __restrict__ row_ptr,
        unsigned* __restrict__ rend, float* __restrict__ dinv) {
    __shared__ unsigned cnt[BKT_N];
    __shared__ unsigned sc[BKT_N];
    __shared__ unsigned nb[BKT_N];
    int b = blockIdx.x;
    int t = threadIdx.x;
    unsigned beg = (unsigned)b * SBKT_CAP;
    unsigned end = min(bbump[b * BBSTRIDE], (unsigned)(b + 1) * SBKT_CAP);
    if (t < BKT_N) cnt[t] = 0u;
    __syncthreads();
    for (unsigned j = beg + (unsigned)t; j < end; j += 256)
        atomicAdd(&cnt[stage[j] & (BKT_N - 1u)], 1u);
    __syncthreads();
    if (t < BKT_N) sc[t] = cnt[t];
    for (int ofs = 1; ofs < BKT_N; ofs <<= 1) {
        __syncthreads();
        unsigned u = (t >= ofs && t < BKT_N) ? sc[t - ofs] : 0u;
        __syncthreads();
        if (t < BKT_N) sc[t] += u;
    }
    __syncthreads();
    if (t < BKT_N) {
        unsigned nodebase = beg + sc[t] - cnt[t];
        int node = (b << BKT_SHIFT) + t;
        row_ptr[node] = nodebase;
        rend[node]    = nodebase + cnt[t];
        dinv[node] = rsqrtf((float)(cnt[t] + 1u));   // +1 self loop
        nb[t] = nodebase;
    }
    __syncthreads();
    for (unsigned j = beg + (unsigned)t; j < end; j += 256) {
        unsigned v = stage[j];
        unsigned pos = atomicAdd(&nb[v & (BKT_N - 1u)], 1u);
        csr[pos] = (int)(v >> BKT_SHIFT);
    }
}

// ------- GEMM1 (2-row blocking, 16 rows/block): xW1h = fp16((x@W1)*dinv) ---
__global__ __launch_bounds__(256) void k_gemm1(
        const float* __restrict__ x, const float* __restrict__ W1,
        const float* __restrict__ dinv, __half* __restrict__ xW1h) {
    __shared__ float W1s[IN_DIM * H1];   // 16 KB
    int tid = threadIdx.x;
    for (int i = tid; i < IN_DIM * H1; i += 256) W1s[i] = W1[i];
    __syncthreads();
    int c = tid & 31, g = tid >> 5;           // 8 groups x 2 rows
    int row0 = blockIdx.x * 16 + g * 2;
    const float4* x0 = reinterpret_cast<const float4*>(x + (size_t)(row0 + 0) * IN_DIM);
    const float4* x1 = reinterpret_cast<const float4*>(x + (size_t)(row0 + 1) * IN_DIM);
    float acc0 = 0.f, acc1 = 0.f;
#pragma unroll 8
    for (int j = 0; j < IN_DIM / 4; ++j) {
        float4 a0 = x0[j], a1 = x1[j];
        float w0 = W1s[(4 * j + 0) * H1 + c];
        float w1 = W1s[(4 * j + 1) * H1 + c];
        float w2 = W1s[(4 * j + 2) * H1 + c];
        float w3 = W1s[(4 * j + 3) * H1 + c];
        acc0 += a0.x * w0 + a0.y * w1 + a0.z * w2 + a0.w * w3;
        acc1 += a1.x * w0 + a1.y * w1 + a1.z * w2 + a1.w * w3;
    }
    xW1h[(size_t)(row0 + 0) * H1 + c] = __float2half(acc0 * dinv[row0 + 0]);
    xW1h[(size_t)(row0 + 1) * H1 + c] = __float2half(acc1 * dinv[row0 + 1]);
}

// ------- gather layer 1 (fp16 rows, 64 B): 16 edge slots x 4 lanes --------
__global__ __launch_bounds__(256) void k_gather1(
        const unsigned* __restrict__ row_ptr, const unsigned* __restrict__ rend,
        const int* __restrict__ csr, const __half* __restrict__ xW1h,
        const float* __restrict__ dinv, float* __restrict__ agg1) {
    int wave = threadIdx.x >> 6;
    int lane = threadIdx.x & 63;
    int q = lane >> 2, t = lane & 3;    // slot q in [0,16), features 8t..8t+7
    int d = blockIdx.x * 4 + wave;
    unsigned beg = row_ptr[d], end = rend[d];
    float acc[8] = {0.f, 0.f, 0.f, 0.f, 0.f, 0.f, 0.f, 0.f};
    for (unsigned j = beg; j < end; j += 32) {
        unsigned j0 = j + (unsigned)q;
        unsigned j1 = j0 + 16u;
        int   s0 = (j0 < end) ? csr[j0] : 0;
        float m0 = (j0 < end) ? 1.f : 0.f;
        int   s1 = (j1 < end) ? csr[j1] : 0;
        float m1 = (j1 < end) ? 1.f : 0.f;
        float4 raw0 = *reinterpret_cast<const float4*>(xW1h + (size_t)s0 * H1 + 8 * t);
        float4 raw1 = *reinterpret_cast<const float4*>(xW1h + (size_t)s1 * H1 + 8 * t);
        const __half2* h0 = reinterpret_cast<const __half2*>(&raw0);
        const __half2* h1 = reinterpret_cast<const __half2*>(&raw1);
#pragma unroll
        for (int i = 0; i < 4; ++i) {
            float2 f0 = __half22float2(h0[i]);
            float2 f1 = __half22float2(h1[i]);
            acc[2 * i]     += f0.x * m0 + f1.x * m1;
            acc[2 * i + 1] += f0.y * m0 + f1.y * m1;
        }
    }
#pragma unroll
    for (int m = 4; m <= 32; m <<= 1)
#pragma unroll
        for (int i = 0; i < 8; ++i)
            acc[i] += __shfl_xor(acc[i], m, 64);
    if (q == 0) {   // lanes 0..3 write the full 32-feature f32 row
        float dv = dinv[d];
        float4 sraw = *reinterpret_cast<const float4*>(xW1h + (size_t)d * H1 + 8 * t);
        const __half2* sh = reinterpret_cast<const __half2*>(&sraw);
        float o[8];
#pragma unroll
        for (int i = 0; i < 4; ++i) {
            float2 f = __half22float2(sh[i]);
            o[2 * i]     = (acc[2 * i] + f.x) * dv;
            o[2 * i + 1] = (acc[2 * i + 1] + f.y) * dv;
        }
        *reinterpret_cast<float4*>(agg1 + (size_t)d * H1 + 8 * t) =
            make_float4(o[0], o[1], o[2], o[3]);
        *reinterpret_cast<float4*>(agg1 + (size_t)d * H1 + 8 * t + 4) =
            make_float4(o[4], o[5], o[6], o[7]);
    }
}

// ------- GEMM2: h2h = fp16( (relu(agg1+b1) @ W2) * dinv[row] ) ------------
__global__ __launch_bounds__(256) void k_gemm2(
        const float* __restrict__ agg1, const float* __restrict__ b1,
        const float* __restrict__ W2, const float* __restrict__ dinv,
        __half* __restrict__ h2h) {
    __shared__ float W2s[H1 * H2];   // 8 KB
    __shared__ float b1s[H1];
    int tid = threadIdx.x;
    for (int i = tid; i < H1 * H2; i += 256) W2s[i] = W2[i];
    if (tid < H1) b1s[tid] = b1[tid];
    __syncthreads();
    int r = tid >> 6, c = tid & 63;
    int row = blockIdx.x * 4 + r;
    if (row >= N_NODES) return;
    float acc = 0.f;
#pragma unroll
    for (int k = 0; k < H1; ++k) {
        float hk = fmaxf(agg1[row * H1 + k] + b1s[k], 0.f);
        acc += hk * W2s[k * H2 + c];
    }
    h2h[row * H2 + c] = __float2half(acc * dinv[row]);
}

// ------- gather layer 2 FUSED with readout (fp16 rows, packed hfma2) ------
// 8 edge slots x 8 lanes; packed fp16 accumulate, f32 flush every 32 edges
// (fp16 accumulator depth <= 4 terms); epilogue + f64 block sum.
__global__ __launch_bounds__(256) void k_gather2_final(
        const unsigned* __restrict__ row_ptr, const unsigned* __restrict__ rend,
        const int* __restrict__ csr, const __half* __restrict__ h2h,
        const float* __restrict__ dinv, const float* __restrict__ b2,
        const float* __restrict__ Wout, double* __restrict__ partial2) {
    int wave = threadIdx.x >> 6;
    int lane = threadIdx.x & 63;
    int o = lane >> 3, t = lane & 7;   // slot o in [0,8), features 8t..8t+7
    int d = blockIdx.x * 4 + wave;
    unsigned beg = row_ptr[d], end = rend[d];
    float acc[8] = {0.f, 0.f, 0.f, 0.f, 0.f, 0.f, 0.f, 0.f};
    const __half2 one2  = __float2half2_rn(1.0f);
    const __half2 zero2 = __float2half2_rn(0.0f);
    for (unsigned base = beg; base < end; base += 32) {
        __half2 hacc[4] = {zero2, zero2, zero2, zero2};
#pragma unroll
        for (int it = 0; it < 2; ++it) {
            unsigned j0 = base + (unsigned)(it * 16) + (unsigned)o;
            unsigned j1 = j0 + 8u;
            int     s0 = (j0 < end) ? csr[j0] : 0;
            __half2 m0 = (j0 < end) ? one2 : zero2;
            int     s1 = (j1 < end) ? csr[j1] : 0;
            __half2 m1 = (j1 < end) ? one2 : zero2;
            float4 raw0 = *reinterpret_cast<const float4*>(h2h + (size_t)s0 * H2 + 8 * t);
            float4 raw1 = *reinterpret_cast<const float4*>(h2h + (size_t)s1 * H2 + 8 * t);
            const __half2* h0 = reinterpret_cast<const __half2*>(&raw0);
            const __half2* h1 = reinterpret_cast<const __half2*>(&raw1);
#pragma unroll
            for (int i = 0; i < 4; ++i) {
                hacc[i] = __hfma2(h0[i], m0, hacc[i]);
                hacc[i] = __hfma2(h1[i], m1, hacc[i]);
            }
        }
#pragma unroll
        for (int i = 0; i < 4; ++i) {
            float2 f = __half22float2(hacc[i]);
            acc[2 * i]     += f.x;
            acc[2 * i + 1] += f.y;
        }
    }
#pragma unroll
    for (int m = 8; m <= 32; m <<= 1)
#pragma unroll
        for (int i = 0; i < 8; ++i)
            acc[i] += __shfl_xor(acc[i], m, 64);
    float dv = dinv[d];
    float4 sraw = *reinterpret_cast<const float4*>(h2h + (size_t)d * H2 + 8 * t);
    const __half2* sh = reinterpret_cast<const __half2*>(&sraw);
    float4 bb0 = *reinterpret_cast<const float4*>(b2 + 8 * t);
    float4 bb1 = *reinterpret_cast<const float4*>(b2 + 8 * t + 4);
    const float* wrow = Wout + (size_t)(d % NPB) * H2 + 8 * t;
    float4 ww0 = *reinterpret_cast<const float4*>(wrow);
    float4 ww1 = *reinterpret_cast<const float4*>(wrow + 4);
    float self[8];
#pragma unroll
    for (int i = 0; i < 4; ++i) {
        float2 f = __half22float2(sh[i]);
        self[2 * i] = f.x; self[2 * i + 1] = f.y;
    }
    float bbv[8] = {bb0.x, bb0.y, bb0.z, bb0.w, bb1.x, bb1.y, bb1.z, bb1.w};
    float wwv[8] = {ww0.x, ww0.y, ww0.z, ww0.w, ww1.x, ww1.y, ww1.z, ww1.w};
    double dval = 0.0;
#pragma unroll
    for (int i = 0; i < 8; ++i)
        dval += (double)(fmaxf((acc[i] + self[i]) * dv + bbv[i], 0.f) * wwv[i]);
    dval += __shfl_down(dval, 4, 64);
    dval += __shfl_down(dval, 2, 64);
    dval += __shfl_down(dval, 1, 64);
    __shared__ double sdbl[4];
    if (lane == 0) sdbl[wave] = dval;
    __syncthreads();
    if (threadIdx.x == 0)
        partial2[blockIdx.x] = (sdbl[0] + sdbl[1]) + (sdbl[2] + sdbl[3]);
}

// ------- final reduce: out[b] = sum of partial2[b*2500 .. ) + bout -------
__global__ __launch_bounds__(256) void k_reduce(
        const double* __restrict__ partial2, const float* __restrict__ bout,
        float* __restrict__ out) {
    int b = blockIdx.x;
    int tid = threadIdx.x;
    double acc = 0.0;
    for (int i = tid; i < BLK_PER_BATCH; i += 256)
        acc += partial2[b * BLK_PER_BATCH + i];
    for (int off = 32; off; off >>= 1) acc += __shfl_down(acc, off, 64);
    __shared__ double sred[4];
    if ((tid & 63) == 0) sred[tid >> 6] = acc;
    __syncthreads();
    if (tid == 0)
        out[b] = (float)(((sred[0] + sred[1]) + (sred[2] + sred[3])) + (double)bout[0]);
}

extern "C" void kernel_launch(void* const* d_in, const int* in_sizes, int n_in,
                              void* d_out, int out_size, void* d_ws, size_t ws_size,
                              hipStream_t stream) {
    const float* x    = (const float*)d_in[0];
    const int*   ei   = (const int*)d_in[1];    // int32 (JAX x64 disabled)
    const float* W1   = (const float*)d_in[2];
    const float* b1   = (const float*)d_in[3];
    const float* W2   = (const float*)d_in[4];
    const float* b2   = (const float*)d_in[5];
    const float* Wout = (const float*)d_in[6];
    const float* bout = (const float*)d_in[7];
    float* out = (float*)d_out;

    // workspace layout — no aliasing, total ~50.5 MB
    constexpr size_t STATIC_SZ = (size_t)NBKT * SBKT_CAP;   // 2.88M entries
    char* ws = (char*)d_ws;
    size_t off = 0;
    int*      csr     = (int*)(ws + off);      off += STATIC_SZ * 4;             // 11.52 MB
    unsigned* stage   = (unsigned*)(ws + off); off += STATIC_SZ * 4;             // 11.52 MB
    __half*   xW1h    = (__half*)(ws + off);   off += (size_t)N_NODES * H1 * 2;  // 5.12 MB
    float*    agg1    = (float*)(ws + off);    off += (size_t)N_NODES * H1 * 4;  // 10.24 MB
    __half*   h2h     = (__half*)(ws + off);   off += (size_t)N_NODES * H2 * 2;  // 10.24 MB
    unsigned* row_ptr = (unsigned*)(ws + off); off += (size_t)N_NODES * 4;       // 0.32 MB
    unsigned* rend    = (unsigned*)(ws + off); off += (size_t)N_NODES * 4;       // 0.32 MB
    float*    dinv    = (float*)(ws + off);    off += (size_t)N_NODES * 4;       // 0.32 MB
    unsigned* bbump   = (unsigned*)(ws + off); off += (size_t)NBKT * BBSTRIDE * 4; // 40 KB
    double*   partial2= (double*)(ws + off);   off += (size_t)G2_BLOCKS * 8;     // 0.16 MB
    (void)ws_size; (void)in_sizes; (void)n_in; (void)out_size;

    const int B = 256;
    k_initb<<<(NBKT + B - 1) / B, B, 0, stream>>>(bbump);
    k_binfill<<<BF_BLOCKS, BF_THREADS, 0, stream>>>(ei, bbump, stage);
    k_place<<<NBKT, B, 0, stream>>>(bbump, stage, csr, row_ptr, rend, dinv);

    k_gemm1<<<N_NODES / 16, B, 0, stream>>>(x, W1, dinv, xW1h);
    k_gather1<<<N_NODES / 4, B, 0, stream>>>(row_ptr, rend, csr, xW1h, dinv, agg1);
    k_gemm2<<<N_NODES / 4, B, 0, stream>>>(agg1, b1, W2, dinv, h2h);
    k_gather2_final<<<G2_BLOCKS, B, 0, stream>>>(row_ptr, rend, csr, h2h, dinv, b2, Wout, partial2);

    k_reduce<<<NB, B, 0, stream>>>(partial2, bout, out);
}

// Round 15
// 234.591 us; speedup vs baseline: 1.0800x; 1.0800x over previous
//
#include <hip/hip_runtime.h>
#include <hip/hip_fp16.h>

// Problem constants (match reference)
constexpr int   N_NODES = 80000;
constexpr int   N_EDGE  = 2560000;
constexpr int   IN_DIM  = 128;
constexpr int   H1      = 32;
constexpr int   H2      = 64;
constexpr int   NPB     = 10000;   // nodes per batch
constexpr int   NB      = 8;       // batches
constexpr int   G2_BLOCKS = N_NODES / 4;        // 20000 (4 nodes per block)
constexpr int   BLK_PER_BATCH = G2_BLOCKS / NB; // 2500

// binned-fill parameters (static bucket capacity, 256 nodes per bucket)
constexpr int   BKT_SHIFT = 8;                       // 256 nodes per bucket
constexpr int   BKT_N     = 1 << BKT_SHIFT;          // 256
constexpr int   NBKT      = (N_NODES + BKT_N - 1) >> BKT_SHIFT;  // 313 (last partial)
constexpr int   BBSTRIDE  = 16;                      // pad bucket counters to 64 B
constexpr unsigned SBKT_CAP = 9216;                  // mean 8192 + ~11 sigma
constexpr int   BF_EPB    = 8192;                    // edges per binfill block
constexpr int   BF_BLOCKS = (N_EDGE + BF_EPB - 1) / BF_EPB;  // 313
constexpr int   BF_THREADS = 512;

// gemm1 grid-stride parameters
constexpr int   G1_TILES  = N_NODES / 32;            // 2500 tiles of 32 rows
constexpr int   G1_BLOCKS = 1024;

// ---------------- seed bucket bumps with static bases ----------------
__global__ void k_initb(unsigned* __restrict__ bbump) {
    int i = blockIdx.x * blockDim.x + threadIdx.x;
    if (i < NBKT) bbump[i * BBSTRIDE] = (unsigned)i * SBKT_CAP;
}

// ------- binned fill: stage[pos] = (src<<8)|d_local, dense per bucket ------
__global__ __launch_bounds__(BF_THREADS) void k_binfill(
        const int* __restrict__ ei, unsigned* __restrict__ bbump,
        unsigned* __restrict__ stage) {
    __shared__ unsigned hist[NBKT];
    __shared__ unsigned base[NBKT];
    int t = threadIdx.x;
    int e0 = blockIdx.x * BF_EPB;
    int e1 = min(e0 + BF_EPB, N_EDGE);
    for (int i = t; i < NBKT; i += BF_THREADS) hist[i] = 0u;
    __syncthreads();
    for (int e = e0 + t; e < e1; e += BF_THREADS) {
        int d = ei[N_EDGE + e];
        atomicAdd(&hist[d >> BKT_SHIFT], 1u);
    }
    __syncthreads();
    for (int i = t; i < NBKT; i += BF_THREADS) {
        unsigned h = hist[i];
        base[i] = h ? atomicAdd(&bbump[i * BBSTRIDE], h) : 0u;
        hist[i] = 0u;
    }
    __syncthreads();
    for (int e = e0 + t; e < e1; e += BF_THREADS) {
        int s = ei[e];
        int d = ei[N_EDGE + e];
        int bkt = d >> BKT_SHIFT;
        unsigned lp = atomicAdd(&hist[bkt], 1u);
        unsigned pos = base[bkt] + lp;
        if (pos < (unsigned)(bkt + 1) * SBKT_CAP)   // capacity guard (never hit)
            stage[pos] = ((unsigned)s << BKT_SHIFT) | (unsigned)(d & (BKT_N - 1));
    }
}

// ------- place: per-bucket degrees (LDS) -> row_ptr, rend, dinv, csr -------
__global__ __launch_bounds__(256) void k_place(
        const unsigned* __restrict__ bbump, const unsigned* __restrict__ stage,
        int* __restrict__ csr, unsigned* __restrict__ row_ptr,
        unsigned* __restrict__ rend, float* __restrict__ dinv) {
    __shared__ unsigned cnt[BKT_N];
    __shared__ unsigned sc[BKT_N];
    __shared__ unsigned nb[BKT_N];
    int b = blockIdx.x;
    int t = threadIdx.x;              // 256 threads == BKT_N
    unsigned beg = (unsigned)b * SBKT_CAP;
    unsigned end = min(bbump[b * BBSTRIDE], (unsigned)(b + 1) * SBKT_CAP);
    cnt[t] = 0u;
    __syncthreads();
    for (unsigned j = beg + (unsigned)t; j < end; j += 256)
        atomicAdd(&cnt[stage[j] & (BKT_N - 1u)], 1u);
    __syncthreads();
    sc[t] = cnt[t];
    for (int ofs = 1; ofs < BKT_N; ofs <<= 1) {
        __syncthreads();
        unsigned u = (t >= ofs) ? sc[t - ofs] : 0u;
        __syncthreads();
        sc[t] += u;
    }
    __syncthreads();
    {
        unsigned nodebase = beg + sc[t] - cnt[t];
        int node = (b << BKT_SHIFT) + t;
        if (node < N_NODES) {
            row_ptr[node] = nodebase;
            rend[node]    = nodebase + cnt[t];
            dinv[node] = rsqrtf((float)(cnt[t] + 1u));   // +1 self loop
        }
        nb[t] = nodebase;
    }
    __syncthreads();
    for (unsigned j = beg + (unsigned)t; j < end; j += 256) {
        unsigned v = stage[j];
        unsigned pos = atomicAdd(&nb[v & (BKT_N - 1u)], 1u);
        csr[pos] = (int)(v >> BKT_SHIFT);
    }
}

// ------- GEMM1 (grid-stride, 4-row blocking): xW1h = fp16((x@W1)*dinv) -----
__global__ __launch_bounds__(256) void k_gemm1(
        const float* __restrict__ x, const float* __restrict__ W1,
        const float* __restrict__ dinv, __half* __restrict__ xW1h) {
    __shared__ float W1s[IN_DIM * H1];   // 16 KB (staged once per block)
    int tid = threadIdx.x;
    for (int i = tid; i < IN_DIM * H1; i += 256) W1s[i] = W1[i];
    __syncthreads();
    int c = tid & 31, g = tid >> 5;           // 8 groups x 4 rows
    for (int tile = blockIdx.x; tile < G1_TILES; tile += G1_BLOCKS) {
        int row0 = tile * 32 + g * 4;
        const float4* x0 = reinterpret_cast<const float4*>(x + (size_t)(row0 + 0) * IN_DIM);
        const float4* x1 = reinterpret_cast<const float4*>(x + (size_t)(row0 + 1) * IN_DIM);
        const float4* x2 = reinterpret_cast<const float4*>(x + (size_t)(row0 + 2) * IN_DIM);
        const float4* x3 = reinterpret_cast<const float4*>(x + (size_t)(row0 + 3) * IN_DIM);
        float acc0 = 0.f, acc1 = 0.f, acc2 = 0.f, acc3 = 0.f;
#pragma unroll 4
        for (int j = 0; j < IN_DIM / 4; ++j) {
            float4 a0 = x0[j], a1 = x1[j], a2 = x2[j], a3 = x3[j];
            float w0 = W1s[(4 * j + 0) * H1 + c];
            float w1 = W1s[(4 * j + 1) * H1 + c];
            float w2 = W1s[(4 * j + 2) * H1 + c];
            float w3 = W1s[(4 * j + 3) * H1 + c];
            acc0 += a0.x * w0 + a0.y * w1 + a0.z * w2 + a0.w * w3;
            acc1 += a1.x * w0 + a1.y * w1 + a1.z * w2 + a1.w * w3;
            acc2 += a2.x * w0 + a2.y * w1 + a2.z * w2 + a2.w * w3;
            acc3 += a3.x * w0 + a3.y * w1 + a3.z * w2 + a3.w * w3;
        }
        xW1h[(size_t)(row0 + 0) * H1 + c] = __float2half(acc0 * dinv[row0 + 0]);
        xW1h[(size_t)(row0 + 1) * H1 + c] = __float2half(acc1 * dinv[row0 + 1]);
        xW1h[(size_t)(row0 + 2) * H1 + c] = __float2half(acc2 * dinv[row0 + 2]);
        xW1h[(size_t)(row0 + 3) * H1 + c] = __float2half(acc3 * dinv[row0 + 3]);
    }
}

// ------- gather layer 1 (fp16 rows, 64 B): 16 edge slots x 4 lanes --------
__global__ __launch_bounds__(256) void k_gather1(
        const unsigned* __restrict__ row_ptr, const unsigned* __restrict__ rend,
        const int* __restrict__ csr, const __half* __restrict__ xW1h,
        const float* __restrict__ dinv, float* __restrict__ agg1) {
    int wave = threadIdx.x >> 6;
    int lane = threadIdx.x & 63;
    int q = lane >> 2, t = lane & 3;    // slot q in [0,16), features 8t..8t+7
    int d = blockIdx.x * 4 + wave;
    unsigned beg = row_ptr[d], end = rend[d];
    float acc[8] = {0.f, 0.f, 0.f, 0.f, 0.f, 0.f, 0.f, 0.f};
    for (unsigned j = beg; j < end; j += 32) {
        unsigned j0 = j + (unsigned)q;
        unsigned j1 = j0 + 16u;
        int   s0 = (j0 < end) ? csr[j0] : 0;
        float m0 = (j0 < end) ? 1.f : 0.f;
        int   s1 = (j1 < end) ? csr[j1] : 0;
        float m1 = (j1 < end) ? 1.f : 0.f;
        float4 raw0 = *reinterpret_cast<const float4*>(xW1h + (size_t)s0 * H1 + 8 * t);
        float4 raw1 = *reinterpret_cast<const float4*>(xW1h + (size_t)s1 * H1 + 8 * t);
        const __half2* h0 = reinterpret_cast<const __half2*>(&raw0);
        const __half2* h1 = reinterpret_cast<const __half2*>(&raw1);
#pragma unroll
        for (int i = 0; i < 4; ++i) {
            float2 f0 = __half22float2(h0[i]);
            float2 f1 = __half22float2(h1[i]);
            acc[2 * i]     += f0.x * m0 + f1.x * m1;
            acc[2 * i + 1] += f0.y * m0 + f1.y * m1;
        }
    }
#pragma unroll
    for (int m = 4; m <= 32; m <<= 1)
#pragma unroll
        for (int i = 0; i < 8; ++i)
            acc[i] += __shfl_xor(acc[i], m, 64);
    if (q == 0) {   // lanes 0..3 write the full 32-feature f32 row
        float dv = dinv[d];
        float4 sraw = *reinterpret_cast<const float4*>(xW1h + (size_t)d * H1 + 8 * t);
        const __half2* sh = reinterpret_cast<const __half2*>(&sraw);
        float o[8];
#pragma unroll
        for (int i = 0; i < 4; ++i) {
            float2 f = __half22float2(sh[i]);
            o[2 * i]     = (acc[2 * i] + f.x) * dv;
            o[2 * i + 1] = (acc[2 * i + 1] + f.y) * dv;
        }
        *reinterpret_cast<float4*>(agg1 + (size_t)d * H1 + 8 * t) =
            make_float4(o[0], o[1], o[2], o[3]);
        *reinterpret_cast<float4*>(agg1 + (size_t)d * H1 + 8 * t + 4) =
            make_float4(o[4], o[5], o[6], o[7]);
    }
}

// ------- GEMM2: h2h = fp16( (relu(agg1+b1) @ W2) * dinv[row] ) ------------
__global__ __launch_bounds__(256) void k_gemm2(
        const float* __restrict__ agg1, const float* __restrict__ b1,
        const float* __restrict__ W2, const float* __restrict__ dinv,
        __half* __restrict__ h2h) {
    __shared__ float W2s[H1 * H2];   // 8 KB
    __shared__ float b1s[H1];
    int tid = threadIdx.x;
    for (int i = tid; i < H1 * H2; i += 256) W2s[i] = W2[i];
    if (tid < H1) b1s[tid] = b1[tid];
    __syncthreads();
    int r = tid >> 6, c = tid & 63;
    int row = blockIdx.x * 4 + r;
    if (row >= N_NODES) return;
    float acc = 0.f;
#pragma unroll
    for (int k = 0; k < H1; ++k) {
        float hk = fmaxf(agg1[row * H1 + k] + b1s[k], 0.f);
        acc += hk * W2s[k * H2 + c];
    }
    h2h[row * H2 + c] = __float2half(acc * dinv[row]);
}

// ------- gather layer 2 FUSED with readout (fp16 rows, packed hfma2) ------
__global__ __launch_bounds__(256) void k_gather2_final(
        const unsigned* __restrict__ row_ptr, const unsigned* __restrict__ rend,
        const int* __restrict__ csr, const __half* __restrict__ h2h,
        const float* __restrict__ dinv, const float* __restrict__ b2,
        const float* __restrict__ Wout, double* __restrict__ partial2) {
    int wave = threadIdx.x >> 6;
    int lane = threadIdx.x & 63;
    int o = lane >> 3, t = lane & 7;   // slot o in [0,8), features 8t..8t+7
    int d = blockIdx.x * 4 + wave;
    unsigned beg = row_ptr[d], end = rend[d];
    float acc[8] = {0.f, 0.f, 0.f, 0.f, 0.f, 0.f, 0.f, 0.f};
    const __half2 one2  = __float2half2_rn(1.0f);
    const __half2 zero2 = __float2half2_rn(0.0f);
    for (unsigned base = beg; base < end; base += 32) {
        __half2 hacc[4] = {zero2, zero2, zero2, zero2};
#pragma unroll
        for (int it = 0; it < 2; ++it) {
            unsigned j0 = base + (unsigned)(it * 16) + (unsigned)o;
            unsigned j1 = j0 + 8u;
            int     s0 = (j0 < end) ? csr[j0] : 0;
            __half2 m0 = (j0 < end) ? one2 : zero2;
            int     s1 = (j1 < end) ? csr[j1] : 0;
            __half2 m1 = (j1 < end) ? one2 : zero2;
            float4 raw0 = *reinterpret_cast<const float4*>(h2h + (size_t)s0 * H2 + 8 * t);
            float4 raw1 = *reinterpret_cast<const float4*>(h2h + (size_t)s1 * H2 + 8 * t);
            const __half2* h0 = reinterpret_cast<const __half2*>(&raw0);
            const __half2* h1 = reinterpret_cast<const __half2*>(&raw1);
#pragma unroll
            for (int i = 0; i < 4; ++i) {
                hacc[i] = __hfma2(h0[i], m0, hacc[i]);
                hacc[i] = __hfma2(h1[i], m1, hacc[i]);
            }
        }
#pragma unroll
        for (int i = 0; i < 4; ++i) {
            float2 f = __half22float2(hacc[i]);
            acc[2 * i]     += f.x;
            acc[2 * i + 1] += f.y;
        }
    }
#pragma unroll
    for (int m = 8; m <= 32; m <<= 1)
#pragma unroll
        for (int i = 0; i < 8; ++i)
            acc[i] += __shfl_xor(acc[i], m, 64);
    float dv = dinv[d];
    float4 sraw = *reinterpret_cast<const float4*>(h2h + (size_t)d * H2 + 8 * t);
    const __half2* sh = reinterpret_cast<const __half2*>(&sraw);
    float4 bb0 = *reinterpret_cast<const float4*>(b2 + 8 * t);
    float4 bb1 = *reinterpret_cast<const float4*>(b2 + 8 * t + 4);
    const float* wrow = Wout + (size_t)(d % NPB) * H2 + 8 * t;
    float4 ww0 = *reinterpret_cast<const float4*>(wrow);
    float4 ww1 = *reinterpret_cast<const float4*>(wrow + 4);
    float self[8];
#pragma unroll
    for (int i = 0; i < 4; ++i) {
        float2 f = __half22float2(sh[i]);
        self[2 * i] = f.x; self[2 * i + 1] = f.y;
    }
    float bbv[8] = {bb0.x, bb0.y, bb0.z, bb0.w, bb1.x, bb1.y, bb1.z, bb1.w};
    float wwv[8] = {ww0.x, ww0.y, ww0.z, ww0.w, ww1.x, ww1.y, ww1.z, ww1.w};
    double dval = 0.0;
#pragma unroll
    for (int i = 0; i < 8; ++i)
        dval += (double)(fmaxf((acc[i] + self[i]) * dv + bbv[i], 0.f) * wwv[i]);
    dval += __shfl_down(dval, 4, 64);
    dval += __shfl_down(dval, 2, 64);
    dval += __shfl_down(dval, 1, 64);
    __shared__ double sdbl[4];
    if (lane == 0) sdbl[wave] = dval;
    __syncthreads();
    if (threadIdx.x == 0)
        partial2[blockIdx.x] = (sdbl[0] + sdbl[1]) + (sdbl[2] + sdbl[3]);
}

// ------- final reduce: out[b] = sum of partial2[b*2500 .. ) + bout -------
__global__ __launch_bounds__(256) void k_reduce(
        const double* __restrict__ partial2, const float* __restrict__ bout,
        float* __restrict__ out) {
    int b = blockIdx.x;
    int tid = threadIdx.x;
    double acc = 0.0;
    for (int i = tid; i < BLK_PER_BATCH; i += 256)
        acc += partial2[b * BLK_PER_BATCH + i];
    for (int off = 32; off; off >>= 1) acc += __shfl_down(acc, off, 64);
    __shared__ double sred[4];
    if ((tid & 63) == 0) sred[tid >> 6] = acc;
    __syncthreads();
    if (tid == 0)
        out[b] = (float)(((sred[0] + sred[1]) + (sred[2] + sred[3])) + (double)bout[0]);
}

extern "C" void kernel_launch(void* const* d_in, const int* in_sizes, int n_in,
                              void* d_out, int out_size, void* d_ws, size_t ws_size,
                              hipStream_t stream) {
    const float* x    = (const float*)d_in[0];
    const int*   ei   = (const int*)d_in[1];    // int32 (JAX x64 disabled)
    const float* W1   = (const float*)d_in[2];
    const float* b1   = (const float*)d_in[3];
    const float* W2   = (const float*)d_in[4];
    const float* b2   = (const float*)d_in[5];
    const float* Wout = (const float*)d_in[6];
    const float* bout = (const float*)d_in[7];
    float* out = (float*)d_out;

    // workspace layout — no aliasing, total ~50.6 MB
    constexpr size_t STATIC_SZ = (size_t)NBKT * SBKT_CAP;   // 2.885M entries
    char* ws = (char*)d_ws;
    size_t off = 0;
    int*      csr     = (int*)(ws + off);      off += STATIC_SZ * 4;             // 11.54 MB
    unsigned* stage   = (unsigned*)(ws + off); off += STATIC_SZ * 4;             // 11.54 MB
    __half*   xW1h    = (__half*)(ws + off);   off += (size_t)N_NODES * H1 * 2;  // 5.12 MB
    float*    agg1    = (float*)(ws + off);    off += (size_t)N_NODES * H1 * 4;  // 10.24 MB
    __half*   h2h     = (__half*)(ws + off);   off += (size_t)N_NODES * H2 * 2;  // 10.24 MB
    unsigned* row_ptr = (unsigned*)(ws + off); off += (size_t)N_NODES * 4;       // 0.32 MB
    unsigned* rend    = (unsigned*)(ws + off); off += (size_t)N_NODES * 4;       // 0.32 MB
    float*    dinv    = (float*)(ws + off);    off += (size_t)N_NODES * 4;       // 0.32 MB
    unsigned* bbump   = (unsigned*)(ws + off); off += (size_t)NBKT * BBSTRIDE * 4; // 20 KB
    double*   partial2= (double*)(ws + off);   off += (size_t)G2_BLOCKS * 8;     // 0.16 MB
    (void)ws_size; (void)in_sizes; (void)n_in; (void)out_size;

    const int B = 256;
    k_initb<<<(NBKT + B - 1) / B, B, 0, stream>>>(bbump);
    k_binfill<<<BF_BLOCKS, BF_THREADS, 0, stream>>>(ei, bbump, stage);
    k_place<<<NBKT, B, 0, stream>>>(bbump, stage, csr, row_ptr, rend, dinv);

    k_gemm1<<<G1_BLOCKS, B, 0, stream>>>(x, W1, dinv, xW1h);
    k_gather1<<<N_NODES / 4, B, 0, stream>>>(row_ptr, rend, csr, xW1h, dinv, agg1);
    k_gemm2<<<N_NODES / 4, B, 0, stream>>>(agg1, b1, W2, dinv, h2h);
    k_gather2_final<<<G2_BLOCKS, B, 0, stream>>>(row_ptr, rend, csr, h2h, dinv, b2, Wout, partial2);

    k_reduce<<<NB, B, 0, stream>>>(partial2, bout, out);
}

// Round 16
// 199.250 us; speedup vs baseline: 1.2715x; 1.1774x over previous
//
#include <hip/hip_runtime.h>
#include <hip/hip_fp16.h>

// Problem constants (match reference)
constexpr int   N_NODES = 80000;
constexpr int   N_EDGE  = 2560000;
constexpr int   IN_DIM  = 128;
constexpr int   H1      = 32;
constexpr int   H2      = 64;
constexpr int   NPB     = 10000;   // nodes per batch
constexpr int   NB      = 8;       // batches
constexpr int   G2_BLOCKS = N_NODES / 4;        // 20000 (4 nodes per block)
constexpr int   BLK_PER_BATCH = G2_BLOCKS / NB; // 2500

// binned-fill parameters (static bucket capacity, 256 nodes per bucket)
constexpr int   BKT_SHIFT = 8;                       // 256 nodes per bucket
constexpr int   BKT_N     = 1 << BKT_SHIFT;          // 256
constexpr int   NBKT      = (N_NODES + BKT_N - 1) >> BKT_SHIFT;  // 313
constexpr int   BBSTRIDE  = 16;                      // pad bucket counters to 64 B
constexpr unsigned SBKT_CAP = 9216;                  // mean 8192 + ~11 sigma
constexpr int   BF_EPB    = 8192;                    // edges per binfill block
constexpr int   BF_BLOCKS = (N_EDGE + BF_EPB - 1) / BF_EPB;  // 313
constexpr int   BF_THREADS = 512;

// gemm1 tile parameters
constexpr int   G1_ROWS   = 64;                      // rows per block tile
constexpr int   G1_BLOCKS = N_NODES / G1_ROWS;       // 1250

// ---------------- seed bucket bumps with static bases ----------------
__global__ void k_initb(unsigned* __restrict__ bbump) {
    int i = blockIdx.x * blockDim.x + threadIdx.x;
    if (i < NBKT) bbump[i * BBSTRIDE] = (unsigned)i * SBKT_CAP;
}

// ------- binned fill: stage[pos] = (src<<8)|d_local, dense per bucket ------
__global__ __launch_bounds__(BF_THREADS) void k_binfill(
        const int* __restrict__ ei, unsigned* __restrict__ bbump,
        unsigned* __restrict__ stage) {
    __shared__ unsigned hist[NBKT];
    __shared__ unsigned base[NBKT];
    int t = threadIdx.x;
    int e0 = blockIdx.x * BF_EPB;
    int e1 = min(e0 + BF_EPB, N_EDGE);
    for (int i = t; i < NBKT; i += BF_THREADS) hist[i] = 0u;
    __syncthreads();
    for (int e = e0 + t; e < e1; e += BF_THREADS) {
        int d = ei[N_EDGE + e];
        atomicAdd(&hist[d >> BKT_SHIFT], 1u);
    }
    __syncthreads();
    for (int i = t; i < NBKT; i += BF_THREADS) {
        unsigned h = hist[i];
        base[i] = h ? atomicAdd(&bbump[i * BBSTRIDE], h) : 0u;
        hist[i] = 0u;
    }
    __syncthreads();
    for (int e = e0 + t; e < e1; e += BF_THREADS) {
        int s = ei[e];
        int d = ei[N_EDGE + e];
        int bkt = d >> BKT_SHIFT;
        unsigned lp = atomicAdd(&hist[bkt], 1u);
        unsigned pos = base[bkt] + lp;
        if (pos < (unsigned)(bkt + 1) * SBKT_CAP)   // capacity guard (never hit)
            stage[pos] = ((unsigned)s << BKT_SHIFT) | (unsigned)(d & (BKT_N - 1));
    }
}

// ------- place: per-bucket degrees (LDS) -> row_ptr, rend, dinv, csr -------
__global__ __launch_bounds__(256) void k_place(
        const unsigned* __restrict__ bbump, const unsigned* __restrict__ stage,
        int* __restrict__ csr, unsigned* __restrict__ row_ptr,
        unsigned* __restrict__ rend, float* __restrict__ dinv) {
    __shared__ unsigned cnt[BKT_N];
    __shared__ unsigned sc[BKT_N];
    __shared__ unsigned nb[BKT_N];
    int b = blockIdx.x;
    int t = threadIdx.x;              // 256 threads == BKT_N
    unsigned beg = (unsigned)b * SBKT_CAP;
    unsigned end = min(bbump[b * BBSTRIDE], (unsigned)(b + 1) * SBKT_CAP);
    cnt[t] = 0u;
    __syncthreads();
    for (unsigned j = beg + (unsigned)t; j < end; j += 256)
        atomicAdd(&cnt[stage[j] & (BKT_N - 1u)], 1u);
    __syncthreads();
    sc[t] = cnt[t];
    for (int ofs = 1; ofs < BKT_N; ofs <<= 1) {
        __syncthreads();
        unsigned u = (t >= ofs) ? sc[t - ofs] : 0u;
        __syncthreads();
        sc[t] += u;
    }
    __syncthreads();
    {
        unsigned nodebase = beg + sc[t] - cnt[t];
        int node = (b << BKT_SHIFT) + t;
        if (node < N_NODES) {
            row_ptr[node] = nodebase;
            rend[node]    = nodebase + cnt[t];
            dinv[node] = rsqrtf((float)(cnt[t] + 1u));   // +1 self loop
        }
        nb[t] = nodebase;
    }
    __syncthreads();
    for (unsigned j = beg + (unsigned)t; j < end; j += 256) {
        unsigned v = stage[j];
        unsigned pos = atomicAdd(&nb[v & (BKT_N - 1u)], 1u);
        csr[pos] = (int)(v >> BKT_SHIFT);
    }
}

// ------- GEMM1 (LDS-staged x-tile, 8-row blocking): xW1h = fp16((x@W1)*dinv)
// Block = 64 rows. x-tile staged COALESCED into LDS (rows contiguous), then
// computed from LDS (broadcast reads are conflict-free). Kills the
// 32x-redundant broadcast global loads diagnosed in rounds 13-15.
__global__ __launch_bounds__(256) void k_gemm1(
        const float* __restrict__ x, const float* __restrict__ W1,
        const float* __restrict__ dinv, __half* __restrict__ xW1h) {
    __shared__ float W1s[IN_DIM * H1];      // 16 KB
    __shared__ float xs[G1_ROWS * IN_DIM];  // 32 KB
    int tid = threadIdx.x;
    for (int i = tid; i < IN_DIM * H1; i += 256) W1s[i] = W1[i];
    // coalesced x-tile stage: 2048 float4, 8 per thread
    int row0 = blockIdx.x * G1_ROWS;
    const float4* src4 = reinterpret_cast<const float4*>(x + (size_t)row0 * IN_DIM);
    float4* xs4 = reinterpret_cast<float4*>(xs);
#pragma unroll
    for (int k = 0; k < 8; ++k) xs4[tid + k * 256] = src4[tid + k * 256];
    __syncthreads();
    int c = tid & 31, g = tid >> 5;   // 8 groups x 8 rows
    float acc[8] = {0.f, 0.f, 0.f, 0.f, 0.f, 0.f, 0.f, 0.f};
    for (int j = 0; j < IN_DIM / 4; ++j) {
        float w0 = W1s[(4 * j + 0) * H1 + c];
        float w1 = W1s[(4 * j + 1) * H1 + c];
        float w2 = W1s[(4 * j + 2) * H1 + c];
        float w3 = W1s[(4 * j + 3) * H1 + c];
#pragma unroll
        for (int r = 0; r < 8; ++r) {
            float4 a = *reinterpret_cast<const float4*>(&xs[((g * 8 + r) << 7) + 4 * j]);
            acc[r] += a.x * w0 + a.y * w1 + a.z * w2 + a.w * w3;
        }
    }
#pragma unroll
    for (int r = 0; r < 8; ++r) {
        int row = row0 + g * 8 + r;
        xW1h[(size_t)row * H1 + c] = __float2half(acc[r] * dinv[row]);
    }
}

// ------- gather layer 1 FUSED with GEMM2 -------
// Gather (fp16 rows, 64 B, 16 slots x 4 lanes) -> after xor-reduce EVERY lane
// holds the full agg1 row (features 8t..8t+7). Then each lane = output column
// c = lane: rel values obtained via 32 compile-time shfls, W2 column held in
// 32 VGPRs. Writes h2h[d][lane] coalesced. agg1 buffer and k_gemm2 deleted.
__global__ __launch_bounds__(256) void k_gather1_gemm2(
        const unsigned* __restrict__ row_ptr, const unsigned* __restrict__ rend,
        const int* __restrict__ csr, const __half* __restrict__ xW1h,
        const float* __restrict__ dinv, const float* __restrict__ b1,
        const float* __restrict__ W2, __half* __restrict__ h2h) {
    int wave = threadIdx.x >> 6;
    int lane = threadIdx.x & 63;
    int q = lane >> 2, t = lane & 3;    // slot q in [0,16), features 8t..8t+7
    int d = blockIdx.x * 4 + wave;
    unsigned beg = row_ptr[d], end = rend[d];
    float acc[8] = {0.f, 0.f, 0.f, 0.f, 0.f, 0.f, 0.f, 0.f};
    for (unsigned j = beg; j < end; j += 32) {
        unsigned j0 = j + (unsigned)q;
        unsigned j1 = j0 + 16u;
        int   s0 = (j0 < end) ? csr[j0] : 0;
        float m0 = (j0 < end) ? 1.f : 0.f;
        int   s1 = (j1 < end) ? csr[j1] : 0;
        float m1 = (j1 < end) ? 1.f : 0.f;
        float4 raw0 = *reinterpret_cast<const float4*>(xW1h + (size_t)s0 * H1 + 8 * t);
        float4 raw1 = *reinterpret_cast<const float4*>(xW1h + (size_t)s1 * H1 + 8 * t);
        const __half2* h0 = reinterpret_cast<const __half2*>(&raw0);
        const __half2* h1 = reinterpret_cast<const __half2*>(&raw1);
#pragma unroll
        for (int i = 0; i < 4; ++i) {
            float2 f0 = __half22float2(h0[i]);
            float2 f1 = __half22float2(h1[i]);
            acc[2 * i]     += f0.x * m0 + f1.x * m1;
            acc[2 * i + 1] += f0.y * m0 + f1.y * m1;
        }
    }
#pragma unroll
    for (int m = 4; m <= 32; m <<= 1)
#pragma unroll
        for (int i = 0; i < 8; ++i)
            acc[i] += __shfl_xor(acc[i], m, 64);
    // ---- fused GEMM2 epilogue (all lanes active) ----
    float dv = dinv[d];
    float4 sraw = *reinterpret_cast<const float4*>(xW1h + (size_t)d * H1 + 8 * t);
    const __half2* sh = reinterpret_cast<const __half2*>(&sraw);
    float rel[8];
#pragma unroll
    for (int i = 0; i < 4; ++i) {
        float2 f = __half22float2(sh[i]);
        rel[2 * i]     = fmaxf((acc[2 * i]     + f.x) * dv + b1[8 * t + 2 * i],     0.f);
        rel[2 * i + 1] = fmaxf((acc[2 * i + 1] + f.y) * dv + b1[8 * t + 2 * i + 1], 0.f);
    }
    // W2 column c = lane (loaded after the gather loop to limit live VGPRs)
    float h2 = 0.f;
#pragma unroll
    for (int k = 0; k < H1; ++k) {
        float w = W2[k * H2 + lane];                 // coalesced, L1/L2-hot
        h2 += __shfl(rel[k & 7], k >> 3, 64) * w;    // src lane t == k>>3
    }
    h2h[(size_t)d * H2 + lane] = __float2half(h2 * dv);
}

// ------- gather layer 2 FUSED with readout (fp16 rows, packed hfma2) ------
__global__ __launch_bounds__(256) void k_gather2_final(
        const unsigned* __restrict__ row_ptr, const unsigned* __restrict__ rend,
        const int* __restrict__ csr, const __half* __restrict__ h2h,
        const float* __restrict__ dinv, const float* __restrict__ b2,
        const float* __restrict__ Wout, double* __restrict__ partial2) {
    int wave = threadIdx.x >> 6;
    int lane = threadIdx.x & 63;
    int o = lane >> 3, t = lane & 7;   // slot o in [0,8), features 8t..8t+7
    int d = blockIdx.x * 4 + wave;
    unsigned beg = row_ptr[d], end = rend[d];
    float acc[8] = {0.f, 0.f, 0.f, 0.f, 0.f, 0.f, 0.f, 0.f};
    const __half2 one2  = __float2half2_rn(1.0f);
    const __half2 zero2 = __float2half2_rn(0.0f);
    for (unsigned base = beg; base < end; base += 32) {
        __half2 hacc[4] = {zero2, zero2, zero2, zero2};
#pragma unroll
        for (int it = 0; it < 2; ++it) {
            unsigned j0 = base + (unsigned)(it * 16) + (unsigned)o;
            unsigned j1 = j0 + 8u;
            int     s0 = (j0 < end) ? csr[j0] : 0;
            __half2 m0 = (j0 < end) ? one2 : zero2;
            int     s1 = (j1 < end) ? csr[j1] : 0;
            __half2 m1 = (j1 < end) ? one2 : zero2;
            float4 raw0 = *reinterpret_cast<const float4*>(h2h + (size_t)s0 * H2 + 8 * t);
            float4 raw1 = *reinterpret_cast<const float4*>(h2h + (size_t)s1 * H2 + 8 * t);
            const __half2* h0 = reinterpret_cast<const __half2*>(&raw0);
            const __half2* h1 = reinterpret_cast<const __half2*>(&raw1);
#pragma unroll
            for (int i = 0; i < 4; ++i) {
                hacc[i] = __hfma2(h0[i], m0, hacc[i]);
                hacc[i] = __hfma2(h1[i], m1, hacc[i]);
            }
        }
#pragma unroll
        for (int i = 0; i < 4; ++i) {
            float2 f = __half22float2(hacc[i]);
            acc[2 * i]     += f.x;
            acc[2 * i + 1] += f.y;
        }
    }
#pragma unroll
    for (int m = 8; m <= 32; m <<= 1)
#pragma unroll
        for (int i = 0; i < 8; ++i)
            acc[i] += __shfl_xor(acc[i], m, 64);
    float dv = dinv[d];
    float4 sraw = *reinterpret_cast<const float4*>(h2h + (size_t)d * H2 + 8 * t);
    const __half2* sh = reinterpret_cast<const __half2*>(&sraw);
    float4 bb0 = *reinterpret_cast<const float4*>(b2 + 8 * t);
    float4 bb1 = *reinterpret_cast<const float4*>(b2 + 8 * t + 4);
    const float* wrow = Wout + (size_t)(d % NPB) * H2 + 8 * t;
    float4 ww0 = *reinterpret_cast<const float4*>(wrow);
    float4 ww1 = *reinterpret_cast<const float4*>(wrow + 4);
    float self[8];
#pragma unroll
    for (int i = 0; i < 4; ++i) {
        float2 f = __half22float2(sh[i]);
        self[2 * i] = f.x; self[2 * i + 1] = f.y;
    }
    float bbv[8] = {bb0.x, bb0.y, bb0.z, bb0.w, bb1.x, bb1.y, bb1.z, bb1.w};
    float wwv[8] = {ww0.x, ww0.y, ww0.z, ww0.w, ww1.x, ww1.y, ww1.z, ww1.w};
    double dval = 0.0;
#pragma unroll
    for (int i = 0; i < 8; ++i)
        dval += (double)(fmaxf((acc[i] + self[i]) * dv + bbv[i], 0.f) * wwv[i]);
    dval += __shfl_down(dval, 4, 64);
    dval += __shfl_down(dval, 2, 64);
    dval += __shfl_down(dval, 1, 64);
    __shared__ double sdbl[4];
    if (lane == 0) sdbl[wave] = dval;
    __syncthreads();
    if (threadIdx.x == 0)
        partial2[blockIdx.x] = (sdbl[0] + sdbl[1]) + (sdbl[2] + sdbl[3]);
}

// ------- final reduce: out[b] = sum of partial2[b*2500 .. ) + bout -------
__global__ __launch_bounds__(256) void k_reduce(
        const double* __restrict__ partial2, const float* __restrict__ bout,
        float* __restrict__ out) {
    int b = blockIdx.x;
    int tid = threadIdx.x;
    double acc = 0.0;
    for (int i = tid; i < BLK_PER_BATCH; i += 256)
        acc += partial2[b * BLK_PER_BATCH + i];
    for (int off = 32; off; off >>= 1) acc += __shfl_down(acc, off, 64);
    __shared__ double sred[4];
    if ((tid & 63) == 0) sred[tid >> 6] = acc;
    __syncthreads();
    if (tid == 0)
        out[b] = (float)(((sred[0] + sred[1]) + (sred[2] + sred[3])) + (double)bout[0]);
}

extern "C" void kernel_launch(void* const* d_in, const int* in_sizes, int n_in,
                              void* d_out, int out_size, void* d_ws, size_t ws_size,
                              hipStream_t stream) {
    const float* x    = (const float*)d_in[0];
    const int*   ei   = (const int*)d_in[1];    // int32 (JAX x64 disabled)
    const float* W1   = (const float*)d_in[2];
    const float* b1   = (const float*)d_in[3];
    const float* W2   = (const float*)d_in[4];
    const float* b2   = (const float*)d_in[5];
    const float* Wout = (const float*)d_in[6];
    const float* bout = (const float*)d_in[7];
    float* out = (float*)d_out;

    // workspace layout — no aliasing, total ~40 MB
    constexpr size_t STATIC_SZ = (size_t)NBKT * SBKT_CAP;   // 2.885M entries
    char* ws = (char*)d_ws;
    size_t off = 0;
    int*      csr     = (int*)(ws + off);      off += STATIC_SZ * 4;             // 11.54 MB
    unsigned* stage   = (unsigned*)(ws + off); off += STATIC_SZ * 4;             // 11.54 MB
    __half*   xW1h    = (__half*)(ws + off);   off += (size_t)N_NODES * H1 * 2;  // 5.12 MB
    __half*   h2h     = (__half*)(ws + off);   off += (size_t)N_NODES * H2 * 2;  // 10.24 MB
    unsigned* row_ptr = (unsigned*)(ws + off); off += (size_t)N_NODES * 4;       // 0.32 MB
    unsigned* rend    = (unsigned*)(ws + off); off += (size_t)N_NODES * 4;       // 0.32 MB
    float*    dinv    = (float*)(ws + off);    off += (size_t)N_NODES * 4;       // 0.32 MB
    unsigned* bbump   = (unsigned*)(ws + off); off += (size_t)NBKT * BBSTRIDE * 4; // 20 KB
    double*   partial2= (double*)(ws + off);   off += (size_t)G2_BLOCKS * 8;     // 0.16 MB
    (void)ws_size; (void)in_sizes; (void)n_in; (void)out_size;

    const int B = 256;
    k_initb<<<(NBKT + B - 1) / B, B, 0, stream>>>(bbump);
    k_binfill<<<BF_BLOCKS, BF_THREADS, 0, stream>>>(ei, bbump, stage);
    k_place<<<NBKT, B, 0, stream>>>(bbump, stage, csr, row_ptr, rend, dinv);

    k_gemm1<<<G1_BLOCKS, B, 0, stream>>>(x, W1, dinv, xW1h);
    k_gather1_gemm2<<<N_NODES / 4, B, 0, stream>>>(row_ptr, rend, csr, xW1h, dinv, b1, W2, h2h);
    k_gather2_final<<<G2_BLOCKS, B, 0, stream>>>(row_ptr, rend, csr, h2h, dinv, b2, Wout, partial2);

    k_reduce<<<NB, B, 0, stream>>>(partial2, bout, out);
}